// Round 1
// baseline (82.718 us; speedup 1.0000x reference)
//
#include <hip/hip_runtime.h>
#include <math.h>

// Quanvolution, closed form for n_layers == 2 (the bench's shape).
//
// Heisenberg picture: push Z_w back through ladder2, RY(beta) layer, ladder1.
// Strings containing Y drop (<Y>=0 for real product states). Under the initial
// product state (layer-0 params folded into data angles): <Z_v>=cos(a_v)=Cv,
// <X_v>=sin(a_v)=Sv. Beta-only coefficients are wave-uniform -> computed
// in-kernel per thread; amortized over 4 patches per thread (2x2 patch tile).

typedef float f4v __attribute__((ext_vector_type(4)));

__device__ __forceinline__ void fsincos(float t, float* s, float* c) {
    // full-angle sin/cos via native HW trig (input in revolutions)
    float r = t * 0.15915494309189535f;   // 1/(2*pi)
    r = r - floorf(r);
    *s = __builtin_amdgcn_sinf(r);
    *c = __builtin_amdgcn_cosf(r);
}

__device__ __forceinline__ f4v ntload4(const float* __restrict__ p) {
    return __builtin_nontemporal_load(reinterpret_cast<const f4v*>(p));
}
__device__ __forceinline__ void ntstore4(float* __restrict__ p, f4v v) {
    __builtin_nontemporal_store(v, reinterpret_cast<f4v*>(p));
}

__device__ __forceinline__ f4v patch_z(float a0, float a1, float a2, float a3,
                                       const float* __restrict__ k) {
    float S0, C0, S1, C1, S2, C2, S3, C3;
    fsincos(a0, &S0, &C0);
    fsincos(a1, &S1, &C1);
    fsincos(a2, &S2, &C2);
    fsincos(a3, &S3, &C3);

    float C0C1 = C0*C1, C2C3 = C2*C3, C1C3 = C1*C3, C0C2 = C0*C2;
    float S0S1 = S0*S1, S1S2 = S1*S2, S0S2 = S0*S2, C2S3 = C2*S3;

    float z0 = k[0]*(C0C1*C3) + k[1]*(S0S1*C2S3) + k[2]*(S1S2*C3) + k[3]*S0;
    float z1 = k[4]*(C0*C2C3) + k[5]*S0S2;
    float z2 = k[6]*C1C3 + k[7]*(C0*(S1S2*C3)) + k[8]*(S0S1*C2) + k[9]*(S0*S3);
    float z3 = k[10]*C0C2 + k[11]*(C1*(S2*S3)) + k[12]*(C0*(S1*S3))
             + k[13]*(S0*(C1*C2C3)) + k[14]*C2S3 + k[15]*(C0C1*S2)
             + k[16]*(S0S2*C3) + k[17]*S1;
    f4v r; r[0] = z0; r[1] = z1; r[2] = z2; r[3] = z3;
    return r;
}

// One thread per 2x2 tile of patches (4 patches, 4x float4 row loads).
__global__ __launch_bounds__(256) void quanv_kernel(
    const float* __restrict__ x,       // (B, 1, 28, 28)
    const float* __restrict__ params,  // (2, 4)
    float* __restrict__ out,           // (B, 784)
    int NT)                            // B * 49 patch-quads
{
    int q = blockIdx.x * blockDim.x + threadIdx.x;
    if (q >= NT) return;

    // ---- wave-uniform: beta coefficients (params loads scalarize) ----
    float cb0, sb0, cb1, sb1, cb2, sb2, cb3, sb3;
    fsincos(params[4], &sb0, &cb0);
    fsincos(params[5], &sb1, &cb1);
    fsincos(params[6], &sb2, &cb2);
    fsincos(params[7], &sb3, &cb3);

    float k[18];
    float cb12 = cb1*cb2, sb12 = sb1*sb2, cb1sb2 = cb1*sb2, sb1cb2 = sb1*cb2;
    k[0]  =  cb12*cb3;      // z0: C0C1C3   (ZZZ)
    k[1]  = -cb12*sb3;      // z0: S0S1C2S3 (ZZX)
    k[2]  = -sb1cb2*cb3;    // z0: S1S2C3   (XZZ)
    k[3]  = -sb12*sb3;      // z0: S0       (XXX)
    k[4]  =  cb0*cb1;       // z1: C0C2C3   (ZZ)
    k[5]  =  sb0*sb1;       // z1: S0S2     (XX)
    k[6]  =  cb0*cb12;      // z2: C1C3     (ZZZ)
    k[7]  = -cb0*sb1cb2;    // z2: C0S1S2C3 (ZXZ)
    k[8]  = -sb0*cb12;      // z2: S0S1C2   (XZZ)
    k[9]  = -sb0*sb12;      // z2: S0S3     (XXX)
    k[10] =  cb0*cb12*cb3;  // z3: C0C2     (ZZZZ)
    k[11] = -cb0*cb1sb2*cb3;// z3: C1S2S3   (ZZXZ)
    k[12] =  cb0*sb12*cb3;  // z3: C0S1S3   (ZXXZ)
    k[13] = -cb0*sb12*sb3;  // z3: S0C1C2C3 (ZXXX)
    k[14] =  sb0*cb12*sb3;  // z3: C2S3     (XZZX)
    k[15] = -sb0*cb1sb2*sb3;// z3: C0C1S2   (XZXX)
    k[16] =  sb0*sb1cb2*cb3;// z3: S0S2C3   (XXZZ)
    k[17] =  sb0*sb12*sb3;  // z3: S1       (XXXX)

    // ---- per-thread: 2x2 patch tile ----
    int b  = q / 49;
    int t  = q - b * 49;
    int v  = t / 7;                    // vertical pair of patch-rows: 2v, 2v+1
    int cp = t - v * 7;                // horizontal pair of patches: cols 4*cp..4*cp+3

    // image rows 4v..4v+3, cols 4cp..4cp+3
    const float* img = x + (size_t)b * 784 + (size_t)v * 112 + (size_t)cp * 4;
    f4v R0 = ntload4(img);
    f4v R1 = ntload4(img + 28);
    f4v R2 = ntload4(img + 56);
    f4v R3 = ntload4(img + 84);

    // layer-0 param fold (wave-uniform scalar loads)
    float p0 = params[0], p1 = params[1], p2 = params[2], p3 = params[3];

    f4v zA = patch_z(R0[0] + p0, R0[1] + p1, R1[0] + p2, R1[1] + p3, k); // (2v,   2cp)
    f4v zB = patch_z(R0[2] + p0, R0[3] + p1, R1[2] + p2, R1[3] + p3, k); // (2v,   2cp+1)
    f4v zC = patch_z(R2[0] + p0, R2[1] + p1, R3[0] + p2, R3[1] + p3, k); // (2v+1, 2cp)
    f4v zD = patch_z(R2[2] + p0, R2[3] + p1, R3[2] + p2, R3[3] + p3, k); // (2v+1, 2cp+1)

    // out float4 index for patch (pr,pc) is b*196 + pr*14 + pc
    float* o = out + ((size_t)b * 196 + (size_t)v * 28 + (size_t)cp * 2) * 4;
    ntstore4(o,          zA);
    ntstore4(o + 4,      zB);
    ntstore4(o + 56,     zC);   // +14 float4s = next patch-row
    ntstore4(o + 60,     zD);
}

extern "C" void kernel_launch(void* const* d_in, const int* in_sizes, int n_in,
                              void* d_out, int out_size, void* d_ws, size_t ws_size,
                              hipStream_t stream) {
    const float* x      = (const float*)d_in[0];
    const float* params = (const float*)d_in[1];
    float* out          = (float*)d_out;
    int B  = in_sizes[0] / 784;          // 8192
    int NT = B * 49;                     // 2x2 patch tiles

    int blocks = (NT + 255) / 256;
    quanv_kernel<<<blocks, 256, 0, stream>>>(x, params, out, NT);
}

// Round 3
// 78.362 us; speedup vs baseline: 1.0556x; 1.0556x over previous
//
#include <hip/hip_runtime.h>
#include <math.h>

// Quanvolution, closed form for n_layers == 2 (the bench's shape).
//
// Heisenberg picture: push Z_w back through ladder2, RY(beta) layer, ladder1.
// Ladder automorphism: Z0->Z1Z2Z3, Z1->Z0Z1, Z2->Z0Z1Z2, Z3->Z0Z1Z2Z3;
// X0->X0X1, X1->X1X2, X2->X2X3, X3->X0X1X3. RY(b): Z->cb*Z - sb*X, X->cb*X + sb*Z.
// Strings containing Y drop (<Y>=0 for real product states). Under the initial
// product state (layer-0 params folded into data angles): <Z_v>=cos(a_v)=Cv,
// <X_v>=sin(a_v)=Sv. Beta-only coefficients are wave-uniform -> computed
// in-kernel per thread (cheaper than a second serialized dispatch).
//
// Roofline note (session): kernel traffic is irreducible 25.7 MB in + 25.7 MB
// out -> ~8.2 us at 6.3 TB/s; measured total dur (~77 us) is dominated by the
// harness's 256 MB poison fill (~44 us) + restores/gaps. 2x2-patch tiling
// (round 1) was neutral within noise and had a worse (strided) store pattern;
// this dense-store 2-patch layout is the best-verified variant.

__device__ __forceinline__ void fsincos(float t, float* s, float* c) {
    // full-angle sin/cos via native HW trig (input in revolutions)
    float r = t * 0.15915494309189535f;   // 1/(2*pi)
    r = r - floorf(r);
    *s = __builtin_amdgcn_sinf(r);
    *c = __builtin_amdgcn_cosf(r);
}

__device__ __forceinline__ float4 patch_z(float a0, float a1, float a2, float a3,
                                          const float* __restrict__ k) {
    float S0, C0, S1, C1, S2, C2, S3, C3;
    fsincos(a0, &S0, &C0);
    fsincos(a1, &S1, &C1);
    fsincos(a2, &S2, &C2);
    fsincos(a3, &S3, &C3);

    float C0C1 = C0*C1, C2C3 = C2*C3, C1C3 = C1*C3, C0C2 = C0*C2;
    float S0S1 = S0*S1, S1S2 = S1*S2, S0S2 = S0*S2, C2S3 = C2*S3;

    float z0 = k[0]*(C0C1*C3) + k[1]*(S0S1*C2S3) + k[2]*(S1S2*C3) + k[3]*S0;
    float z1 = k[4]*(C0*C2C3) + k[5]*S0S2;
    float z2 = k[6]*C1C3 + k[7]*(C0*(S1S2*C3)) + k[8]*(S0S1*C2) + k[9]*(S0*S3);
    float z3 = k[10]*C0C2 + k[11]*(C1*(S2*S3)) + k[12]*(C0*(S1*S3))
             + k[13]*(S0*(C1*C2C3)) + k[14]*C2S3 + k[15]*(C0C1*S2)
             + k[16]*(S0S2*C3) + k[17]*S1;
    return make_float4(z0, z1, z2, z3);
}

// One thread per pair of horizontally-adjacent patches (float4 row loads).
__global__ __launch_bounds__(256) void quanv_kernel(
    const float* __restrict__ x,       // (B, 1, 28, 28)
    const float* __restrict__ params,  // (2, 4)
    float* __restrict__ out,           // (B, 784)
    int NP)                            // B * 98 patch-pairs
{
    int q = blockIdx.x * blockDim.x + threadIdx.x;
    if (q >= NP) return;

    // ---- wave-uniform: beta coefficients (params loads scalarize) ----
    float cb0, sb0, cb1, sb1, cb2, sb2, cb3, sb3;
    fsincos(params[4], &sb0, &cb0);
    fsincos(params[5], &sb1, &cb1);
    fsincos(params[6], &sb2, &cb2);
    fsincos(params[7], &sb3, &cb3);

    float k[18];
    float cb12 = cb1*cb2, sb12 = sb1*sb2, cb1sb2 = cb1*sb2, sb1cb2 = sb1*cb2;
    k[0]  =  cb12*cb3;      // z0: C0C1C3   (ZZZ)
    k[1]  = -cb12*sb3;      // z0: S0S1C2S3 (ZZX)
    k[2]  = -sb1cb2*cb3;    // z0: S1S2C3   (XZZ)
    k[3]  = -sb12*sb3;      // z0: S0       (XXX)
    k[4]  =  cb0*cb1;       // z1: C0C2C3   (ZZ)
    k[5]  =  sb0*sb1;       // z1: S0S2     (XX)
    k[6]  =  cb0*cb12;      // z2: C1C3     (ZZZ)
    k[7]  = -cb0*sb1cb2;    // z2: C0S1S2C3 (ZXZ)
    k[8]  = -sb0*cb12;      // z2: S0S1C2   (XZZ)
    k[9]  = -sb0*sb12;      // z2: S0S3     (XXX)
    k[10] =  cb0*cb12*cb3;  // z3: C0C2     (ZZZZ)
    k[11] = -cb0*cb1sb2*cb3;// z3: C1S2S3   (ZZXZ)
    k[12] =  cb0*sb12*cb3;  // z3: C0S1S3   (ZXXZ)
    k[13] = -cb0*sb12*sb3;  // z3: S0C1C2C3 (ZXXX)
    k[14] =  sb0*cb12*sb3;  // z3: C2S3     (XZZX)
    k[15] = -sb0*cb1sb2*sb3;// z3: C0C1S2   (XZXX)
    k[16] =  sb0*sb1cb2*cb3;// z3: S0S2C3   (XXZZ)
    k[17] =  sb0*sb12*sb3;  // z3: S1       (XXXX)

    // ---- per-thread: two patches ----
    int b  = q / 98;
    int t  = q - b * 98;
    int r  = t / 7;
    int cp = t - r * 7;                // pair index within row: cols 4*cp .. 4*cp+3

    const float* img = x + (size_t)b * 784 + (size_t)r * 56 + (size_t)cp * 4;
    float4 row0 = *reinterpret_cast<const float4*>(img);
    float4 row1 = *reinterpret_cast<const float4*>(img + 28);

    // layer-0 param fold (wave-uniform scalar loads)
    float p0 = params[0], p1 = params[1], p2 = params[2], p3 = params[3];

    float4 zA = patch_z(row0.x + p0, row0.y + p1, row1.x + p2, row1.y + p3, k);
    float4 zB = patch_z(row0.z + p0, row0.w + p1, row1.z + p2, row1.w + p3, k);

    // out[b, (r*14 + 2*cp)*4 ...] == out[8*q ...]
    float4* o = reinterpret_cast<float4*>(out) + 2 * (size_t)q;
    o[0] = zA;
    o[1] = zB;
}

extern "C" void kernel_launch(void* const* d_in, const int* in_sizes, int n_in,
                              void* d_out, int out_size, void* d_ws, size_t ws_size,
                              hipStream_t stream) {
    const float* x      = (const float*)d_in[0];
    const float* params = (const float*)d_in[1];
    float* out          = (float*)d_out;
    int B  = in_sizes[0] / 784;          // 8192
    int NP = B * 98;                     // patch pairs

    int blocks = (NP + 255) / 256;
    quanv_kernel<<<blocks, 256, 0, stream>>>(x, params, out, NP);
}